// Round 1
// baseline (215.236 us; speedup 1.0000x reference)
//
#include <hip/hip_runtime.h>
#include <math.h>

namespace {

constexpr int B_ = 256;
constexpr int R_ = 1152;
constexpr int C_ = 10;
constexpr int O_ = 16;
constexpr int I_ = 8;
constexpr int CO_ = C_ * O_;          // 160
constexpr int WRI_ = C_ * O_ * I_;    // 1280 floats of W per route

constexpr int KS2_ = 72;              // r-splits in k_s5
constexpr int RC2_ = R_ / KS2_;       // 16 routes per block
constexpr int BH_  = 128;             // batch-half per k_s5 block
constexpr int RT_  = 4;               // routes per k_a4 block
constexpr int NBLK_ = 640;            // CO_ * (B_/64)

// fallback tier-3 params
constexpr int KSF_ = 16;
constexpr int RCF_ = R_ / KSF_;       // 72
constexpr int MBF_ = 16;

// ws layout (float offsets)
constexpr size_t XT_OFF    = 0;                          // [R][B][I]
constexpr size_t XT_N      = (size_t)R_ * B_ * I_;       // 2,359,296
constexpr size_t SP_OFF    = XT_OFF + XT_N;              // [CO][KS2][B]
constexpr size_t SP_N      = (size_t)CO_ * KS2_ * B_;    // 2,949,120
constexpr size_t V_OFF     = SP_OFF + SP_N;              // [B][CO]
constexpr size_t V_N       = (size_t)B_ * CO_;           // 40,960
constexpr size_t BIJ_OFF   = V_OFF + V_N;                // [C][R]
constexpr size_t BIJ_N     = (size_t)C_ * R_;            // 11,520
constexpr size_t FL_TOTAL  = BIJ_OFF + BIJ_N;

__device__ __forceinline__ float squashf(float s) {
    // faithful to reference: s^2*s/((1+s^2)*sqrt(s^2)) == s*|s|/(1+s^2)
    return s * fabsf(s) / (1.0f + s * s);
}

// ===========================================================================
// k_tr2: x[b,r,i] -> xT[r,b,i] (+ zero bijT).  tile 8 b x 32 r.  grid 1152.
// ===========================================================================
__global__ __launch_bounds__(256) void k_tr2(const float* __restrict__ x,
                                             float* __restrict__ xT,
                                             float* __restrict__ bijT) {
    __shared__ float t[8][32][8];
    const int tid = threadIdx.x;
    {
        const int gi = blockIdx.x * 256 + tid;
        if (gi < C_ * R_) bijT[gi] = 0.f;
    }
    const int r0 = (blockIdx.x % 36) * 32;
    const int b0 = (blockIdx.x / 36) * 8;
    {
        const int rl = tid & 31, bl = tid >> 5;
        const float4* p = (const float4*)(x + ((size_t)(b0 + bl) * R_ + (r0 + rl)) * I_);
        const float4 a0 = p[0], a1 = p[1];
        float* d = &t[bl][rl][0];
        *(float4*)d = a0;
        *(float4*)(d + 4) = a1;
    }
    __syncthreads();
    {
        const int f = tid & 7, rw = tid >> 3;   // f = b-local
        const float* s8 = &t[f][rw][0];
        const float4 a0 = *(const float4*)s8, a1 = *(const float4*)(s8 + 4);
        float* d = xT + ((size_t)(r0 + rw) * B_ + (b0 + f)) * I_;
        *(float4*)d = a0;
        *(float4*)(d + 4) = a1;
    }
}

// ===========================================================================
// k_s5 (rev): spart[c*O+o, ks, b] = sum_{r in chunk} cw[r,c] *
//                                   dot(W[r,c,o,:], xT[r,b,:])
// grid (C_, KS2_, 2): block = (capsule c, 16-route chunk, batch-half).
// 256 thr = 4 waves; wave owns a 4-o tile over the block's 128 b's
// (acc[4][2], lane = b%64).
//
// KEY CHANGE vs prior version: the x chunk (16 r x 128 b x 8 i = 64 KB) is
// staged ONCE into LDS and shared by all 4 o-waves, instead of each wave
// re-reading all b-groups from global (was a 40x L2/L3 re-read of xT =
// 377 MB/launch; xT (9.4 MB) doesn't fit a 4 MiB XCD L2 -> L3-bound).
// x LDS layout is XOR-swizzled on the float4 index (e' = e ^ ((e>>3)&7)):
// the natural 32B-stride per-lane b128 read is a 16-way bank conflict,
// swizzled it is balanced (8 lanes per 4-bank group).
// cw[r] is folded into the staged W once per block -> inner loop is pure
// fma: 64 fma + 4 x-LDS reads + 8 broadcast W-reads per r per thread.
// LDS total ~72.3 KB -> 2 blocks/CU.
// ===========================================================================
template <bool UNIFORM>
__global__ __launch_bounds__(256) void k_s5(const float* __restrict__ xT,
                                            const float* __restrict__ Wm,
                                            const float* __restrict__ bijT,
                                            float* __restrict__ spart) {
    __shared__ __align__(16) float4 xl[RC2_ * 256];    // 64 KB, swizzled
    __shared__ __align__(16) float  wl[RC2_ * 128];    // 8 KB, cw-scaled
    __shared__ float cwch[RC2_];
    __shared__ float sred[8];

    const int tid  = threadIdx.x;
    const int lane = tid & 63;
    const int c    = blockIdx.x;          // 0..9
    const int ks   = blockIdx.y;          // 0..KS2_-1
    const int bh   = blockIdx.z;          // 0..1
    const int r0   = ks * RC2_;

    // ---- softmax over routes for capsule c -> cwch[0..15] ----
    if (!UNIFORM) {
        const float* bc = bijT + (size_t)c * R_;
        float bv[5];
        #pragma unroll
        for (int k = 0; k < 5; ++k) {
            const int r = tid + 256 * k;
            bv[k] = (r < R_) ? bc[r] : -1e30f;
        }
        float m = -1e30f;
        #pragma unroll
        for (int k = 0; k < 5; ++k) m = fmaxf(m, bv[k]);
        #pragma unroll
        for (int off = 32; off > 0; off >>= 1)
            m = fmaxf(m, __shfl_down(m, off, 64));
        if (lane == 0) sred[tid >> 6] = m;
        __syncthreads();
        const float bm = fmaxf(fmaxf(sred[0], sred[1]), fmaxf(sred[2], sred[3]));
        float se = 0.f;
        #pragma unroll
        for (int k = 0; k < 5; ++k)
            se += (bv[k] > -1e29f) ? expf(bv[k] - bm) : 0.f;
        #pragma unroll
        for (int off = 32; off > 0; off >>= 1)
            se += __shfl_down(se, off, 64);
        if (lane == 0) sred[4 + (tid >> 6)] = se;
        __syncthreads();
        const float inv = 1.0f / (sred[4] + sred[5] + sred[6] + sred[7]);
        if (tid < RC2_) cwch[tid] = expf(bc[r0 + tid] - bm) * inv;
    }
    __syncthreads();

    // ---- stage cw-scaled W chunk: rows r0..r0+15, capsule c ----
    {
        const float4* src = (const float4*)(Wm + ((size_t)r0 * C_ + c) * 128);
        float4* dst = (float4*)wl;
        #pragma unroll
        for (int k = 0; k < (RC2_ * 32) / 256; ++k) {      // 2 iters
            const int idx = tid + 256 * k;                 // 0..511
            const int r = idx >> 5, q = idx & 31;
            float4 wv = src[(size_t)r * (C_ * 32) + q];
            const float cw = UNIFORM ? (1.0f / (float)R_) : cwch[r];
            wv.x *= cw; wv.y *= cw; wv.z *= cw; wv.w *= cw;
            dst[idx] = wv;
        }
    }
    // ---- stage x chunk (swizzled): 16 r x 128 b x 8 i ----
    {
        const float4* src = (const float4*)(xT + ((size_t)r0 * B_ + bh * BH_) * I_);
        #pragma unroll
        for (int k = 0; k < (RC2_ * 256) / 256; ++k) {     // 16 iters
            const int idx = tid + 256 * k;                 // 0..4095
            const int r = idx >> 8, er = idx & 255;        // er = 2*b + h
            xl[r * 256 + (er ^ ((er >> 3) & 7))] = src[(size_t)r * 512 + er];
        }
    }
    __syncthreads();

    const int o0 = (tid >> 6) * 4;        // wave-uniform; LDS W reads broadcast

    // per-thread swizzled x indices: bb=0 -> b=lane; bb=1 -> +128 (swizzle
    // only touches bits 0..2, so +64 b == +128 f4 is swizzle-invariant)
    const int e00 = (2 * lane) ^ ((lane >> 2) & 7);        // h=0 slot
    const int e01 = e00 ^ 1;                               // h=1 slot

    float acc[4][2];
    #pragma unroll
    for (int oo = 0; oo < 4; ++oo)
        #pragma unroll
        for (int bb = 0; bb < 2; ++bb) acc[oo][bb] = 0.f;

    #pragma unroll 4
    for (int r = 0; r < RC2_; ++r) {
        const int ra = r * 256;
        const float4 a00 = xl[ra + e00];
        const float4 a01 = xl[ra + e01];
        const float4 a10 = xl[ra + 128 + e00];
        const float4 a11 = xl[ra + 128 + e01];
        float xr[2][8];
        xr[0][0] = a00.x; xr[0][1] = a00.y; xr[0][2] = a00.z; xr[0][3] = a00.w;
        xr[0][4] = a01.x; xr[0][5] = a01.y; xr[0][6] = a01.z; xr[0][7] = a01.w;
        xr[1][0] = a10.x; xr[1][1] = a10.y; xr[1][2] = a10.z; xr[1][3] = a10.w;
        xr[1][4] = a11.x; xr[1][5] = a11.y; xr[1][6] = a11.z; xr[1][7] = a11.w;

        const float4* wp = (const float4*)&wl[r * 128 + o0 * 8];
        #pragma unroll
        for (int oo = 0; oo < 4; ++oo) {
            const float4 w0 = wp[oo * 2 + 0];
            const float4 w1 = wp[oo * 2 + 1];
            #pragma unroll
            for (int bb = 0; bb < 2; ++bb) {
                float a = acc[oo][bb];
                a = fmaf(xr[bb][0], w0.x, a);
                a = fmaf(xr[bb][1], w0.y, a);
                a = fmaf(xr[bb][2], w0.z, a);
                a = fmaf(xr[bb][3], w0.w, a);
                a = fmaf(xr[bb][4], w1.x, a);
                a = fmaf(xr[bb][5], w1.y, a);
                a = fmaf(xr[bb][6], w1.z, a);
                a = fmaf(xr[bb][7], w1.w, a);
                acc[oo][bb] = a;
            }
        }
    }

    // store: spart[c*O + o0+oo][ks][bh*128 + bb*64 + lane]  (lane-contiguous)
    float* sp = spart + (((size_t)(c * O_ + o0)) * KS2_ + ks) * B_ + bh * BH_ + lane;
    #pragma unroll
    for (int oo = 0; oo < 4; ++oo)
        #pragma unroll
        for (int bb = 0; bb < 2; ++bb)
            sp[(size_t)oo * KS2_ * B_ + bb * 64] = acc[oo][bb];
}

// ===========================================================================
// k_v3: vout[b,co] = squash(sum_ks spart[co,ks,b]).  grid NBLK_, 256 thr.
// 4 wave-groups of 18 ks-partials each.
// ===========================================================================
__global__ __launch_bounds__(256) void k_v3(const float* __restrict__ spart,
                                            float* __restrict__ vout) {
    __shared__ float sh[192];
    const int tid  = threadIdx.x;
    const int lane = tid & 63;
    const int g    = tid >> 6;
    const int co2  = blockIdx.x % CO_;
    const int bseg = blockIdx.x / CO_;
    const float* p = spart + (((size_t)co2) * KS2_ + g * 18) * B_ + bseg * 64 + lane;
    float t0 = 0.f, t1 = 0.f;
    #pragma unroll
    for (int j = 0; j < 18; j += 2) {
        t0 += p[(size_t)(j + 0) * B_];
        t1 += p[(size_t)(j + 1) * B_];
    }
    const float s = t0 + t1;
    if (g) sh[(g - 1) * 64 + lane] = s;
    __syncthreads();
    if (g == 0) {
        const float tot = s + sh[lane] + sh[64 + lane] + sh[128 + lane];
        const int b = bseg * 64 + lane;
        vout[(size_t)b * CO_ + co2] = squashf(tot);
    }
}

// ===========================================================================
// k_a4: bijT[c, r0+rr] += (1/B) sum_o sum_i W[r,c,o,i]*(sum_b v[b,c,o]*xT[r,b,i])
// grid R_/RT_ blocks, 640 thr = 160 co x 4 b-groups of 64.
// ===========================================================================
__global__ __launch_bounds__(640) void k_a4(const float* __restrict__ xT,
                                            const float* __restrict__ Wm,
                                            const float* __restrict__ v,
                                            float* __restrict__ bijT) {
    __shared__ __align__(16) float xrow[RT_ * B_ * I_];
    __shared__ float part[RT_][640];

    const int tid = threadIdx.x;
    const int r0  = blockIdx.x * RT_;

    for (int k = tid; k < RT_ * B_ * I_ / 4; k += 640)
        ((float4*)xrow)[k] = ((const float4*)(xT + (size_t)r0 * B_ * I_))[k];
    __syncthreads();

    const int co = tid % CO_;
    const int bg = tid / CO_;
    const int b0 = bg * 64;

    float acc[RT_][8];
    #pragma unroll
    for (int rr = 0; rr < RT_; ++rr)
        #pragma unroll
        for (int i = 0; i < 8; ++i) acc[rr][i] = 0.f;

    const float* vp = v + co;
    #pragma unroll 2
    for (int bb = 0; bb < 64; ++bb) {
        const int b = b0 + bb;
        const float vt = vp[(size_t)b * CO_];
        #pragma unroll
        for (int rr = 0; rr < RT_; ++rr) {
            const float4 y0 = *(const float4*)(&xrow[(rr * B_ + b) * I_]);
            const float4 y1 = *(const float4*)(&xrow[(rr * B_ + b) * I_ + 4]);
            acc[rr][0] = fmaf(vt, y0.x, acc[rr][0]);
            acc[rr][1] = fmaf(vt, y0.y, acc[rr][1]);
            acc[rr][2] = fmaf(vt, y0.z, acc[rr][2]);
            acc[rr][3] = fmaf(vt, y0.w, acc[rr][3]);
            acc[rr][4] = fmaf(vt, y1.x, acc[rr][4]);
            acc[rr][5] = fmaf(vt, y1.y, acc[rr][5]);
            acc[rr][6] = fmaf(vt, y1.z, acc[rr][6]);
            acc[rr][7] = fmaf(vt, y1.w, acc[rr][7]);
        }
    }

    #pragma unroll
    for (int rr = 0; rr < RT_; ++rr) {
        const float* wp = Wm + (((size_t)(r0 + rr)) * CO_ + co) * I_;
        const float4 w0 = *(const float4*)wp;
        const float4 w1 = *(const float4*)(wp + 4);
        const float p0 = fmaf(acc[rr][1], w0.y, acc[rr][0] * w0.x);
        const float p1 = fmaf(acc[rr][3], w0.w, acc[rr][2] * w0.z);
        const float p2 = fmaf(acc[rr][5], w1.y, acc[rr][4] * w1.x);
        const float p3 = fmaf(acc[rr][7], w1.w, acc[rr][6] * w1.z);
        part[rr][tid] = (p0 + p1) + (p2 + p3);
    }
    __syncthreads();

    if (tid < CO_) {
        #pragma unroll
        for (int rr = 0; rr < RT_; ++rr) {
            float a = part[rr][tid] + part[rr][CO_ + tid] +
                      part[rr][2 * CO_ + tid] + part[rr][3 * CO_ + tid];
            #pragma unroll
            for (int off = 8; off > 0; off >>= 1)
                a += __shfl_down(a, off, 16);
            if ((tid & 15) == 0)
                bijT[(size_t)(tid >> 4) * R_ + (r0 + rr)] += a * (1.0f / (float)B_);
        }
    }
}

// ===========================================================================
// FALLBACK tier 3 (tiny ws)
// ===========================================================================
template <bool UNIFORM>
__global__ __launch_bounds__(256) void k_s_f(const float* __restrict__ x,
                                             const float* __restrict__ Wm,
                                             const float* __restrict__ cij,
                                             float* __restrict__ s_out) {
    const int o  = threadIdx.x & 15;
    const int tb = threadIdx.x >> 4;
    const int b  = blockIdx.z * MBF_ + tb;
    const int c  = blockIdx.y;
    const int r0 = blockIdx.x * RCF_;

    const float* xp = x + ((size_t)b * R_ + r0) * I_;
    const float* wp = Wm + (((size_t)r0 * C_ + c) * O_ + o) * I_;
    const float* cp = cij + (size_t)r0 * C_ + c;

    float acc = 0.f;
    #pragma unroll 4
    for (int r = 0; r < RCF_; ++r) {
        const float4 xv0 = *(const float4*)(xp);
        const float4 xv1 = *(const float4*)(xp + 4);
        const float4 wv0 = *(const float4*)(wp);
        const float4 wv1 = *(const float4*)(wp + 4);
        const float p0 = fmaf(xv0.y, wv0.y, xv0.x * wv0.x);
        const float p1 = fmaf(xv0.w, wv0.w, xv0.z * wv0.z);
        const float p2 = fmaf(xv1.y, wv1.y, xv1.x * wv1.x);
        const float p3 = fmaf(xv1.w, wv1.w, xv1.z * wv1.z);
        const float cw = UNIFORM ? (1.0f / (float)R_) : cp[0];
        acc = fmaf(cw, (p0 + p1) + (p2 + p3), acc);
        xp += I_;
        wp += WRI_;
        cp += C_;
    }
    atomicAdd(&s_out[((size_t)b * C_ + c) * O_ + o], acc);
}

__global__ __launch_bounds__(256) void k_a_f(const float* __restrict__ x,
                                             const float* __restrict__ Wm,
                                             const float* __restrict__ s_in,
                                             float* __restrict__ amean) {
    __shared__ __align__(16) float wlds[2 * WRI_];
    __shared__ float red[4][2 * C_];

    const int tid = threadIdx.x;
    const int r0  = blockIdx.x * 2;

    const float* wsrc = Wm + (size_t)r0 * WRI_;
    #pragma unroll
    for (int k = 0; k < 2 * WRI_ / 256; ++k)
        wlds[tid + 256 * k] = wsrc[tid + 256 * k];
    __syncthreads();

    const int b    = tid;
    const int lane = tid & 63;
    const int wv   = tid >> 6;

    float xv[2][I_];
    const float4* xp4 = (const float4*)(x + ((size_t)b * R_ + r0) * I_);
    #pragma unroll
    for (int rr = 0; rr < 2; ++rr) {
        const float4 a0 = xp4[rr * 2 + 0];
        const float4 a1 = xp4[rr * 2 + 1];
        xv[rr][0] = a0.x; xv[rr][1] = a0.y; xv[rr][2] = a0.z; xv[rr][3] = a0.w;
        xv[rr][4] = a1.x; xv[rr][5] = a1.y; xv[rr][6] = a1.z; xv[rr][7] = a1.w;
    }

    #pragma unroll 1
    for (int c = 0; c < C_; ++c) {
        const float4* sp4 = (const float4*)(s_in + ((size_t)b * C_ + c) * O_);
        float v[O_];
        #pragma unroll
        for (int q = 0; q < 4; ++q) {
            const float4 sv = sp4[q];
            v[q * 4 + 0] = squashf(sv.x);
            v[q * 4 + 1] = squashf(sv.y);
            v[q * 4 + 2] = squashf(sv.z);
            v[q * 4 + 3] = squashf(sv.w);
        }
        #pragma unroll 1
        for (int rr = 0; rr < 2; ++rr) {
            const float4* wl4 = (const float4*)&wlds[(rr * C_ + c) * O_ * I_];
            float a = 0.f;
            #pragma unroll
            for (int o = 0; o < O_; ++o) {
                const float4 w0 = wl4[o * 2 + 0];
                const float4 w1 = wl4[o * 2 + 1];
                float u = xv[rr][0] * w0.x;
                u = fmaf(xv[rr][1], w0.y, u);
                u = fmaf(xv[rr][2], w0.z, u);
                u = fmaf(xv[rr][3], w0.w, u);
                u = fmaf(xv[rr][4], w1.x, u);
                u = fmaf(xv[rr][5], w1.y, u);
                u = fmaf(xv[rr][6], w1.z, u);
                u = fmaf(xv[rr][7], w1.w, u);
                a = fmaf(u, v[o], a);
            }
            #pragma unroll
            for (int off = 32; off > 0; off >>= 1)
                a += __shfl_down(a, off, 64);
            if (lane == 0) red[wv][rr * C_ + c] = a;
        }
    }

    __syncthreads();
    if (tid < 2 * C_) {
        const float t = red[0][tid] + red[1][tid] + red[2][tid] + red[3][tid];
        const int rr = tid / C_;
        const int c  = tid % C_;
        amean[(size_t)(r0 + rr) * C_ + c] = t * (1.0f / (float)B_);
    }
}

__global__ __launch_bounds__(256) void k_soft(const float* __restrict__ amean,
                                              float* __restrict__ bij,
                                              float* __restrict__ cij) {
    const int c   = blockIdx.x;
    const int tid = threadIdx.x;
    __shared__ float sred[4];

    float vals[5];
    float m = -1e30f;
    #pragma unroll
    for (int k = 0; k < 5; ++k) {
        const int r = tid + 256 * k;
        if (r < R_) {
            const size_t idx = (size_t)r * C_ + c;
            const float vv = bij[idx] + amean[idx];
            bij[idx] = vv;
            vals[k] = vv;
            m = fmaxf(m, vv);
        } else {
            vals[k] = -1e30f;
        }
    }
    #pragma unroll
    for (int off = 32; off > 0; off >>= 1)
        m = fmaxf(m, __shfl_down(m, off, 64));
    if ((tid & 63) == 0) sred[tid >> 6] = m;
    __syncthreads();
    const float bm = fmaxf(fmaxf(sred[0], sred[1]), fmaxf(sred[2], sred[3]));
    __syncthreads();

    float se = 0.f;
    #pragma unroll
    for (int k = 0; k < 5; ++k)
        se += (vals[k] > -1e29f) ? expf(vals[k] - bm) : 0.f;
    #pragma unroll
    for (int off = 32; off > 0; off >>= 1)
        se += __shfl_down(se, off, 64);
    if ((tid & 63) == 0) sred[tid >> 6] = se;
    __syncthreads();
    const float inv = 1.0f / (sred[0] + sred[1] + sred[2] + sred[3]);

    #pragma unroll
    for (int k = 0; k < 5; ++k) {
        const int r = tid + 256 * k;
        if (r < R_) cij[(size_t)r * C_ + c] = expf(vals[k] - bm) * inv;
    }
}

__global__ __launch_bounds__(256) void k_squash(float* __restrict__ s) {
    const int idx = blockIdx.x * 256 + threadIdx.x;
    if (idx < B_ * CO_) s[idx] = squashf(s[idx]);
}

} // namespace

extern "C" void kernel_launch(void* const* d_in, const int* in_sizes, int n_in,
                              void* d_out, int out_size, void* d_ws, size_t ws_size,
                              hipStream_t stream) {
    const float* x  = (const float*)d_in[0];   // [256,1152,8]
    const float* Wm = (const float*)d_in[1];   // [1152,10,16,8]
    float* out = (float*)d_out;                // [256,10,16] flat = 40960
    float* ws  = (float*)d_ws;

    const size_t need = FL_TOTAL * sizeof(float);

    if (ws_size >= need) {
        // ---------------- main path: 9 nodes ----------------
        float* xT    = ws + XT_OFF;
        float* spart = ws + SP_OFF;
        float* v     = ws + V_OFF;
        float* bijT  = ws + BIJ_OFF;

        const dim3 gs(C_, KS2_, 2);               // 1440 blocks

        k_tr2<<<1152, 256, 0, stream>>>(x, xT, bijT);

        // iter 0 (uniform weights; softmax(0) == 1/R)
        k_s5<true><<<gs, 256, 0, stream>>>(xT, Wm, bijT, spart);
        k_v3<<<NBLK_, 256, 0, stream>>>(spart, v);
        k_a4<<<R_ / RT_, 640, 0, stream>>>(xT, Wm, v, bijT);

        // iter 1
        k_s5<false><<<gs, 256, 0, stream>>>(xT, Wm, bijT, spart);
        k_v3<<<NBLK_, 256, 0, stream>>>(spart, v);
        k_a4<<<R_ / RT_, 640, 0, stream>>>(xT, Wm, v, bijT);

        // iter 2: final v straight into d_out
        k_s5<false><<<gs, 256, 0, stream>>>(xT, Wm, bijT, spart);
        k_v3<<<NBLK_, 256, 0, stream>>>(spart, out);
    } else {
        // ---------------- tier 3 ----------------
        float* s_buf = ws;
        float* cij   = ws + 40960;
        float* bij   = cij + R_ * C_;
        float* amean = bij + R_ * C_;

        const dim3 gsf(KSF_, C_, B_ / MBF_);

        hipMemsetAsync(bij, 0, R_ * C_ * sizeof(float), stream);

        hipMemsetAsync(s_buf, 0, B_ * CO_ * sizeof(float), stream);
        k_s_f<true><<<gsf, 256, 0, stream>>>(x, Wm, cij, s_buf);
        k_a_f<<<R_ / 2, 256, 0, stream>>>(x, Wm, s_buf, amean);
        k_soft<<<C_, 256, 0, stream>>>(amean, bij, cij);

        hipMemsetAsync(s_buf, 0, B_ * CO_ * sizeof(float), stream);
        k_s_f<false><<<gsf, 256, 0, stream>>>(x, Wm, cij, s_buf);
        k_a_f<<<R_ / 2, 256, 0, stream>>>(x, Wm, s_buf, amean);
        k_soft<<<C_, 256, 0, stream>>>(amean, bij, cij);

        hipMemsetAsync(out, 0, B_ * CO_ * sizeof(float), stream);
        k_s_f<false><<<gsf, 256, 0, stream>>>(x, Wm, cij, out);
        k_squash<<<(B_ * CO_ + 255) / 256, 256, 0, stream>>>(out);
    }
}